// Round 2
// baseline (400.251 us; speedup 1.0000x reference)
//
#include <hip/hip_runtime.h>

typedef unsigned short u16;
typedef short s16x8 __attribute__((ext_vector_type(8)));
typedef float f32x16 __attribute__((ext_vector_type(16)));

#define NBATCH 16384

__device__ __forceinline__ u16 tobf(float f){
  unsigned int v = __builtin_bit_cast(unsigned int, f);
  v += 0x7FFFu + ((v >> 16) & 1u);
  return (u16)(v >> 16);
}
__device__ __forceinline__ float lrelu(float x){ return fmaxf(x, 0.1f*x); }

// ---------------- kernel P: parameter repack / folding ----------------
// w2f layout: [e][mt(4)][kk(12)][lane(64)][j(8)] bf16  (A-fragment order for
// v_mfma_f32_32x32x16_bf16, global K ordering k = dk*64 + ic)
__global__ void kp(const float* __restrict__ c2w, const float* __restrict__ c2b,
                   const float* __restrict__ g2,  const float* __restrict__ b2,
                   const float* __restrict__ m2,  const float* __restrict__ v2,
                   const float* __restrict__ fcw,
                   const float* __restrict__ c1b, const float* __restrict__ g1,
                   const float* __restrict__ b1,  const float* __restrict__ m1,
                   const float* __restrict__ v1,
                   u16* __restrict__ w2f, float* __restrict__ fwa,
                   float* __restrict__ c2f, float* __restrict__ c1f)
{
  int gid = blockIdx.x*blockDim.x + threadIdx.x;
  int gsz = gridDim.x*blockDim.x;
  for (int i = gid; i < 4*4*12*64*8; i += gsz){
    int j = i & 7, l = (i >> 3) & 63;
    int r2 = i >> 9;
    int kk = r2 % 12, r3 = r2 / 12;
    int mt = r3 & 3, e = r3 >> 2;
    int kl = 4*(l >> 5) + (j & 3) + 8*(j >> 2);   // k within 16-step
    int dk = kk >> 2, ic = (kk & 3)*16 + kl;      // k = kk*16+kl = dk*64+ic
    int oc = mt*32 + (l & 31);
    w2f[i] = tobf(c2w[((e*128 + oc)*64 + ic)*3 + dk]);
  }
  for (int i = gid; i < 512; i += gsz){          // per (e,oc): fold BN2 + fc
    int e = i >> 7, oc = i & 127;
    float A2 = g2[i] / sqrtf(v2[i] + 1e-5f);
    float B2 = c2b[i]*A2 + b2[i] - m2[i]*A2;
    c2f[i] = B2 / A2;                             // A2>0 (bn2 gamma = 1)
    for (int s = 0; s < 32; s++)
      fwa[i*32 + s] = (s < 30) ? A2 * fcw[e*3840 + oc*30 + s] : 0.f;
  }
  for (int i = gid; i < 256; i += gsz){          // fold BN1 + conv1 bias
    float A1 = g1[i] / sqrtf(v1[i] + 1e-5f);
    float B1 = c1b[i]*A1 + b1[i] - m1[i]*A1;
    c1f[2*i] = A1; c1f[2*i+1] = B1;
  }
}

// ---------------- kernel G: per-batch ctx / gates / base / wide ----------------
__global__ void kg(const float* __restrict__ x,
                   const float* __restrict__ bw, const float* __restrict__ bb,
                   const float* __restrict__ ww, const float* __restrict__ wb,
                   const float* __restrict__ gtw1, const float* __restrict__ gtb1,
                   const float* __restrict__ gtw2, const float* __restrict__ gtb2,
                   const float* __restrict__ gcw1, const float* __restrict__ gcb1,
                   const float* __restrict__ gcw2, const float* __restrict__ gcb2,
                   const float* __restrict__ mgw1, const float* __restrict__ mgb1,
                   const float* __restrict__ mgw2, const float* __restrict__ mgb2,
                   float* __restrict__ coef, float* __restrict__ rest)
{
  const int lane = threadIdx.x & 63;
  const int b = blockIdx.x*4 + (threadIdx.x >> 6);
  const float* xb = x + b*60;
  float xv = (lane < 60) ? xb[lane] : 0.f;        // lane = s*2+c

  // per-channel mean (parity reduce over lanes with same bit0)
  float sm = xv;
  #pragma unroll
  for (int o = 2; o < 64; o <<= 1) sm += __shfl_xor(sm, o, 64);
  float mean = sm * (1.f/30.f);
  float dd = (lane < 60) ? (xv - mean) : 0.f;
  float dv = dd*dd;
  #pragma unroll
  for (int o = 2; o < 64; o <<= 1) dv += __shfl_xor(dv, o, 64);
  float sd = sqrtf(dv * (1.f/29.f));              // ddof=1
  float meanB = __shfl_xor(mean, 1, 64), sdB = __shfl_xor(sd, 1, 64);
  float c0m = (lane & 1) ? meanB : mean, c1m = (lane & 1) ? mean : meanB;
  float c0s = (lane & 1) ? sdB : sd,     c1s = (lane & 1) ? sd : sdB;
  float xl0 = __shfl(xv, 58, 64), xl1 = __shfl(xv, 59, 64);
  float ctx[6] = {c0m, c1m, c0s, c1s, xl0, xl1};

  float bs = (lane < 60) ? xv * bw[lane] : 0.f;
  #pragma unroll
  for (int o = 1; o < 64; o <<= 1) bs += __shfl_xor(bs, o, 64);
  float base = bs + bb[0];
  float wide = xl0*ww[0] + xl1*ww[1] + wb[0];
  float restv = xl0 + base + wide;

  // gate t
  float hg = gtb1[lane];
  #pragma unroll
  for (int i = 0; i < 6; i++) hg += ctx[i]*gtw1[lane*6 + i];
  hg = lrelu(hg);
  float z0 = hg*gtw2[lane], z1 = hg*gtw2[64 + lane];
  #pragma unroll
  for (int o = 1; o < 64; o <<= 1){ z0 += __shfl_xor(z0, o, 64); z1 += __shfl_xor(z1, o, 64); }
  z0 += gtb2[0]; z1 += gtb2[1];
  float wt0 = 1.f/(1.f + expf(z1 - z0)), wt1 = 1.f - wt0;

  // gate c
  float hc = gcb1[lane];
  #pragma unroll
  for (int i = 0; i < 6; i++) hc += ctx[i]*gcw1[lane*6 + i];
  hc = lrelu(hc);
  float y0 = hc*gcw2[lane], y1 = hc*gcw2[64 + lane];
  #pragma unroll
  for (int o = 1; o < 64; o <<= 1){ y0 += __shfl_xor(y0, o, 64); y1 += __shfl_xor(y1, o, 64); }
  y0 += gcb2[0]; y1 += gcb2[1];
  float wc0 = 1.f/(1.f + expf(y1 - y0)), wc1 = 1.f - wc0;

  // meta gate (32 hidden)
  float hm = 0.f;
  if (lane < 32){
    float t2 = mgb1[lane];
    #pragma unroll
    for (int i = 0; i < 6; i++) t2 += ctx[i]*mgw1[lane*6 + i];
    t2 = lrelu(t2);
    hm = t2 * mgw2[lane];
  }
  #pragma unroll
  for (int o = 1; o < 64; o <<= 1) hm += __shfl_xor(hm, o, 64);
  float alpha = 1.f/(1.f + expf(-(hm + mgb2[0])));

  if (lane == 0){
    rest[b] = restv;
    float4 cf = make_float4(alpha*wt0, alpha*wt1, alpha*wc0, alpha*wc1);
    *(float4*)(coef + b*4) = cf;
  }
}

// ---------------- kernel F: fused decomp -> conv1 -> conv2(MFMA) -> fc ----------------
// grid (1024, 4): blockIdx.y = expert; block = 256 threads = 4 waves.
// Per iteration: 2 batches. Wave w: q = w>>1 (batch in pair), h = w&1 (oc half).
__global__ __launch_bounds__(256, 2) void kf(
    const float* __restrict__ x, const float* __restrict__ dw,
    const float* __restrict__ c1w, const float* __restrict__ c1f,
    const u16* __restrict__ w2f, const float* __restrict__ c2f,
    const float* __restrict__ fwa, float* __restrict__ oute)
{
  const int tid = threadIdx.x;
  const int e = blockIdx.y;
  const int lane = tid & 63;
  const int wv = tid >> 6;
  const int h = wv & 1, q = wv >> 1;
  const int sN = lane & 31, gp = lane >> 5;

  __shared__ __align__(16) unsigned char h1b[2*2*32*128]; // [buf][q][row 0..31][128B], XOR-swizzled
  __shared__ __align__(16) float ts[2][2][32];            // [q][ic][s'] trend/seasonal, pad rows 0,31
  __shared__ float partial[2][2][2];                      // [parity][q][h]

  { // zero pad rows 0,31 of every (buf,q) h1 tile
    int region = tid >> 5;
    int buf_ = region >> 2, qq = (region >> 1) & 1, row = (region & 1) ? 31 : 0;
    *(unsigned int*)(h1b + (((buf_*2 + qq)*32 + row)*128) + (tid & 31)*4) = 0u;
  }
  if (tid < 8){
    int qq = tid >> 2, ic = (tid >> 1) & 1, rr = (tid & 1) ? 31 : 0;
    ts[qq][ic][rr] = 0.f;
  }

  // conv1 thread role: cq = batch-of-pair, oc1 = out channel, sh = s-half
  const int cq = tid >> 7;
  const int oc1 = tid & 63;
  const int sh = (tid >> 6) & 1;
  float W1[6], A1, B1f;
  {
    const float* p = c1w + (e*64 + oc1)*6;
    #pragma unroll
    for (int i = 0; i < 6; i++) W1[i] = p[i];
    A1 = c1f[(e*64 + oc1)*2]; B1f = c1f[(e*64 + oc1)*2 + 1];
  }
  // ic-permutation (within 16-groups: swap bits 2<->3) -> byte column
  const int pp2 = (((oc1 & 48) | (oc1 & 3) | ((oc1 & 4) << 1) | ((oc1 & 8) >> 1))) * 2;

  // W2 A-fragments, register resident (2 M-tiles x 12 K-steps)
  s16x8 af[2][12];
  #pragma unroll
  for (int mt = 0; mt < 2; mt++)
    #pragma unroll
    for (int kk = 0; kk < 12; kk++)
      af[mt][kk] = *(const s16x8*)(w2f + (((e*4 + (2*h + mt))*12 + kk)*64 + lane)*8);

  // epilogue tables, register resident (fixed per lane across all batches)
  float C2r[32], FWr[32];
  #pragma unroll
  for (int mt = 0; mt < 2; mt++)
    #pragma unroll
    for (int r = 0; r < 16; r++){
      int oc = (2*h + mt)*32 + (r & 3) + 8*(r >> 2) + 4*gp;   // C/D row mapping
      C2r[mt*16 + r] = c2f[e*128 + oc];
      FWr[mt*16 + r] = fwa[(e*128 + oc)*32 + sN];
    }

  __syncthreads();

  const int tile0 = blockIdx.x * 16;

  auto do_trend = [&](int t){
    if (tid < 120){
      int qq = tid / 60, r2 = tid - qq*60;
      int s = r2 >> 1, c = r2 & 1;
      const float* xb = x + (tile0 + 2*t + qq)*60;
      float acc = 0.f;
      #pragma unroll
      for (int k = 0; k < 15; k++){
        int s2 = s + k - 7;
        if (s2 >= 0 && s2 < 30) acc += xb[s2*2 + c] * dw[c*15 + k];
      }
      float v = (e < 2) ? acc : (xb[s*2 + c] - acc);
      ts[qq][c][s + 1] = v;
    }
  };

  auto do_conv1 = [&](int buf){
    float wA[2][18];
    #pragma unroll
    for (int ic = 0; ic < 2; ic++){
      const float* bp = &ts[cq][ic][sh*16];
      float4 v0 = ((const float4*)bp)[0];
      float4 v1 = ((const float4*)bp)[1];
      float4 v2 = ((const float4*)bp)[2];
      float4 v3 = ((const float4*)bp)[3];
      wA[ic][0]=v0.x;  wA[ic][1]=v0.y;  wA[ic][2]=v0.z;  wA[ic][3]=v0.w;
      wA[ic][4]=v1.x;  wA[ic][5]=v1.y;  wA[ic][6]=v1.z;  wA[ic][7]=v1.w;
      wA[ic][8]=v2.x;  wA[ic][9]=v2.y;  wA[ic][10]=v2.z; wA[ic][11]=v2.w;
      wA[ic][12]=v3.x; wA[ic][13]=v3.y; wA[ic][14]=v3.z; wA[ic][15]=v3.w;
      if (sh == 0){
        float2 vx = *(const float2*)(&ts[cq][ic][16]);
        wA[ic][16] = vx.x; wA[ic][17] = vx.y;
      } else { wA[ic][16] = 0.f; wA[ic][17] = 0.f; }
    }
    unsigned char* hb = h1b + (buf*2 + cq)*4096;
    #pragma unroll
    for (int si = 0; si < 16; si++){
      if (sh == 1 && si >= 14) continue;     // half1 covers s=16..29 only
      float z = wA[0][si]*W1[0] + wA[0][si+1]*W1[1] + wA[0][si+2]*W1[2]
              + wA[1][si]*W1[3] + wA[1][si+1]*W1[4] + wA[1][si+2]*W1[5];
      float hh = lrelu(z*A1 + B1f);
      int row = sh*16 + si + 1;
      *(u16*)(hb + row*128 + (pp2 ^ ((row & 7) << 4))) = tobf(hh);
    }
  };

  auto do_mfma = [&](int t, int buf){
    f32x16 a0, a1;
    #pragma unroll
    for (int i = 0; i < 16; i++){ a0[i] = 0.f; a1[i] = 0.f; }
    const unsigned char* hb = h1b + (buf*2 + q)*4096;
    #pragma unroll
    for (int kk = 0; kk < 12; kk++){
      const int dk = kk >> 2, icb = kk & 3;
      int row = sN + dk; row = (row > 31) ? 31 : row;   // s>=30 lanes: junk, masked by FWr=0
      const s16x8 bv = *(const s16x8*)(hb + row*128 + ((icb*32 + gp*16) ^ ((row & 7) << 4)));
      a0 = __builtin_amdgcn_mfma_f32_32x32x16_bf16(af[0][kk], bv, a0, 0, 0, 0);
      a1 = __builtin_amdgcn_mfma_f32_32x32x16_bf16(af[1][kk], bv, a1, 0, 0, 0);
    }
    float sum = 0.f;
    #pragma unroll
    for (int r = 0; r < 16; r++){
      float z0 = a0[r] + C2r[r];      sum += lrelu(z0) * FWr[r];
      float z1 = a1[r] + C2r[16 + r]; sum += lrelu(z1) * FWr[16 + r];
    }
    #pragma unroll
    for (int o = 1; o < 64; o <<= 1) sum += __shfl_xor(sum, o, 64);
    if (lane == 0) partial[t & 1][q][h] = sum;
  };

  do_trend(0);
  __syncthreads();
  do_conv1(0);
  __syncthreads();
  #pragma unroll 1
  for (int t = 0; t < 8; t++){
    if (t + 1 < 8) do_trend(t + 1);
    __syncthreads();
    if (t + 1 < 8) do_conv1((t + 1) & 1);
    do_mfma(t, t & 1);
    __syncthreads();
    if (tid < 2)
      oute[e*NBATCH + tile0 + 2*t + tid] = partial[t & 1][tid][0] + partial[t & 1][tid][1];
  }
}

// ---------------- kernel C: combine ----------------
__global__ void kc(const float* __restrict__ rest, const float* __restrict__ coef,
                   const float* __restrict__ oute, const float* __restrict__ fcb,
                   float* __restrict__ out)
{
  int b = blockIdx.x*256 + threadIdx.x;
  float r = rest[b];
  float4 cf = *(const float4*)(coef + b*4);
  float o0 = oute[b]            + fcb[0];
  float o1 = oute[NBATCH + b]   + fcb[1];
  float o2 = oute[2*NBATCH + b] + fcb[2];
  float o3 = oute[3*NBATCH + b] + fcb[3];
  float tot = r + cf.x*o0 + cf.y*o1 + cf.z*o2 + cf.w*o3;
  out[b] = tot;
  out[NBATCH + b] = r;
}

extern "C" void kernel_launch(void* const* d_in, const int* in_sizes, int n_in,
                              void* d_out, int out_size, void* d_ws, size_t ws_size,
                              hipStream_t stream)
{
  const float* x    = (const float*)d_in[0];
  const float* dw   = (const float*)d_in[1];
  const float* c1w  = (const float*)d_in[2];
  const float* c1b  = (const float*)d_in[3];
  const float* g1   = (const float*)d_in[4];
  const float* b1   = (const float*)d_in[5];
  const float* m1   = (const float*)d_in[6];
  const float* v1   = (const float*)d_in[7];
  const float* c2w  = (const float*)d_in[8];
  const float* c2b  = (const float*)d_in[9];
  const float* g2   = (const float*)d_in[10];
  const float* b2   = (const float*)d_in[11];
  const float* m2   = (const float*)d_in[12];
  const float* v2   = (const float*)d_in[13];
  const float* fcw  = (const float*)d_in[14];
  const float* fcb  = (const float*)d_in[15];
  const float* bw   = (const float*)d_in[16];
  const float* bb   = (const float*)d_in[17];
  const float* ww   = (const float*)d_in[18];
  const float* wb   = (const float*)d_in[19];
  const float* gtw1 = (const float*)d_in[20];
  const float* gtb1 = (const float*)d_in[21];
  const float* gtw2 = (const float*)d_in[22];
  const float* gtb2 = (const float*)d_in[23];
  const float* gcw1 = (const float*)d_in[24];
  const float* gcb1 = (const float*)d_in[25];
  const float* gcw2 = (const float*)d_in[26];
  const float* gcb2 = (const float*)d_in[27];
  const float* mgw1 = (const float*)d_in[28];
  const float* mgb1 = (const float*)d_in[29];
  const float* mgw2 = (const float*)d_in[30];
  const float* mgb2 = (const float*)d_in[31];

  char* ws = (char*)d_ws;
  u16*   w2f  = (u16*)  (ws + 0);        // 196608 B
  float* fwa  = (float*)(ws + 196608);   // 65536 B
  float* c2f  = (float*)(ws + 262144);   // 2048 B
  float* c1f  = (float*)(ws + 264192);   // 2048 B
  float* coef = (float*)(ws + 266240);   // 262144 B
  float* rest = (float*)(ws + 528384);   // 65536 B
  float* oute = (float*)(ws + 593920);   // 262144 B
  float* out = (float*)d_out;

  kp<<<dim3(192), dim3(256), 0, stream>>>(c2w, c2b, g2, b2, m2, v2, fcw,
                                          c1b, g1, b1, m1, v1, w2f, fwa, c2f, c1f);
  kg<<<dim3(4096), dim3(256), 0, stream>>>(x, bw, bb, ww, wb,
                                           gtw1, gtb1, gtw2, gtb2,
                                           gcw1, gcb1, gcw2, gcb2,
                                           mgw1, mgb1, mgw2, mgb2, coef, rest);
  kf<<<dim3(1024, 4), dim3(256), 0, stream>>>(x, dw, c1w, c1f, w2f, c2f, fwa, oute);
  kc<<<dim3(64), dim3(256), 0, stream>>>(rest, coef, oute, fcb, out);
}